// Round 1
// baseline (470.864 us; speedup 1.0000x reference)
//
#include <hip/hip_runtime.h>
#include <math.h>

// Problem constants
#define BB   2
#define CC   256
#define HH   256
#define WW   512
#define HW   (HH*WW)        // 131072
#define IMG  (CC*HW)        // per-batch x block
#define NPIX (BB*HW)        // 262144

// Padded evident layout: [B][13][HP][WP], 16-halo of zeros on all sides
#define HP   (HH+32)        // 288
#define WP   (WW+32)        // 544
#define CHP  (HP*WP)        // 156672 floats per channel plane
#define EVB  (13*CHP)       // per-batch evident block
#define EV_FLOATS (BB*EVB)  // 4073472 floats = 16.3 MB

// Output layout (flat concat): x_cls [2,1,256,512] | x_reg [2,1,256,512] | x_off [2,2,256,512]
#define OUT_REG (BB*HW)     // 262144
#define OUT_OFF (2*BB*HW)   // 524288

// ---------------------------------------------------------------------------
// Repack weights into wp[c][16] (c-major, 16 contiguous output channels) so the
// main kernel can read them with uniform (scalar) loads. Also pack 16 biases.
__global__ void repack_w(const float* __restrict__ pw, const float* __restrict__ pb,
                         const float* __restrict__ rw, const float* __restrict__ rb,
                         const float* __restrict__ ow, const float* __restrict__ ob,
                         float* __restrict__ wp, float* __restrict__ bias) {
    int i = blockIdx.x * blockDim.x + threadIdx.x;
    if (i < 4096) {
        int c = i >> 4, o = i & 15;
        float v;
        if (o < 13)       v = pw[o * CC + c];
        else if (o == 13) v = rw[c];
        else              v = ow[(o - 14) * CC + c];
        wp[c * 16 + o] = v;
    }
    if (i < 16) {
        float v = (i < 13) ? pb[i] : (i == 13 ? rb[0] : ob[i - 14]);
        bias[i] = v;
    }
}

// ---------------------------------------------------------------------------
// Fused 1x1 convs: 16 output channels per pixel. Each thread handles 2
// consecutive pixels (float2 coalesced loads, 512 B per wave per channel).
// Channels 0..12 -> relu -> padded evident (workspace); 13 -> x_reg; 14,15 -> x_off.
__global__ __launch_bounds__(256) void conv1x1_k(
    const float* __restrict__ x, const float* __restrict__ wp,
    const float* __restrict__ bias, float* __restrict__ ev,
    float* __restrict__ out) {
    int g  = blockIdx.x * 256 + threadIdx.x;   // 131072 threads
    int p  = g * 2;
    int b  = p >> 17;
    int hw = p & (HW - 1);
    const float* xb = x + (size_t)b * IMG + hw;

    float acc0[16], acc1[16];
#pragma unroll
    for (int o = 0; o < 16; o++) { acc0[o] = 0.f; acc1[o] = 0.f; }

#pragma unroll 4
    for (int c = 0; c < CC; c++) {
        float2 v = *(const float2*)(xb + c * HW);
        const float* wr = wp + c * 16;   // uniform address -> s_load
#pragma unroll
        for (int o = 0; o < 16; o++) {
            float wv = wr[o];
            acc0[o] = fmaf(v.x, wv, acc0[o]);
            acc1[o] = fmaf(v.y, wv, acc1[o]);
        }
    }

    int y0 = hw >> 9, x0 = hw & 511;
    int hw1 = hw + 1;
    int y1 = hw1 >> 9, x1 = hw1 & 511;
    float* evb = ev + (size_t)b * EVB;
#pragma unroll
    for (int o = 0; o < 13; o++) {
        float bo = bias[o];
        float e0 = fmaxf(acc0[o] + bo, 0.f);
        float e1 = fmaxf(acc1[o] + bo, 0.f);
        evb[o * CHP + (y0 + 16) * WP + (x0 + 16)] = e0;
        evb[o * CHP + (y1 + 16) * WP + (x1 + 16)] = e1;
    }
    float rbv = bias[13];
    out[OUT_REG + b * HW + hw]     = acc0[13] + rbv;
    out[OUT_REG + b * HW + hw + 1] = acc1[13] + rbv;
#pragma unroll
    for (int o = 14; o < 16; o++) {
        float bo = bias[o];
        out[OUT_OFF + b * 2 * HW + (o - 14) * HW + hw]     = acc0[o] + bo;
        out[OUT_OFF + b * 2 * HW + (o - 14) * HW + hw + 1] = acc1[o] + bo;
    }
}

// ---------------------------------------------------------------------------
// Hough vote conv (33x33, 13 regions) + sigmoid.
// score[y,x] = sum_{ky,kx} evident[region(16-ky,16-kx), y+ky-16, x+kx-16] / count[region]
// Per-tap channel+spatial offset folded into one LDS table entry; padded
// evident means no bounds checks in the 1089-tap loop.
__global__ __launch_bounds__(256) void hough_k(const float* __restrict__ ev,
                                               float* __restrict__ out) {
    __shared__ int   t_off[1089];
    __shared__ float t_wgt[1089];
    __shared__ int   cnt[13];
    int tid = threadIdx.x;
    if (tid < 13) cnt[tid] = 0;
    __syncthreads();

    for (int i = tid; i < 1089; i += 256) {
        int ky = i / 33, kx = i - ky * 33;
        int ys = 16 - ky, xs = 16 - kx;          // filter-source coords (flip folded in)
        int r2 = ys * ys + xs * xs;
        int bin;
        if (ys == 0)     bin = (xs >= 0) ? 0 : 2;
        else if (ys > 0) bin = (xs > 0) ? 0 : 1;
        else             bin = (xs < 0) ? 2 : 3;
        int c;
        if (r2 <= 4)        c = 0;
        else if (r2 <= 64)  c = 1 + bin;
        else if (r2 <= 256) c = 5 + bin;
        else                c = 9 + bin;
        t_off[i] = c;                             // temp: region id
        atomicAdd(&cnt[c], 1);
    }
    __syncthreads();

    for (int i = tid; i < 1089; i += 256) {
        int ky = i / 33, kx = i - ky * 33;
        int c  = t_off[i];
        t_wgt[i] = 1.0f / (float)cnt[c];
        t_off[i] = c * CHP + (ky - 16) * WP + (kx - 16);
    }
    __syncthreads();

    int p  = blockIdx.x * 256 + tid;
    int b  = p >> 17;
    int hw = p & (HW - 1);
    int y  = hw >> 9, xx = hw & 511;
    const float* pc = ev + (size_t)b * EVB + (y + 16) * WP + (xx + 16);

    float s = 0.f;
#pragma unroll 8
    for (int t = 0; t < 1089; t++) {
        s = fmaf(pc[t_off[t]], t_wgt[t], s);
    }
    float cls = 1.0f / (1.0f + expf(-s));
    out[b * HW + hw] = cls;
}

// ---------------------------------------------------------------------------
extern "C" void kernel_launch(void* const* d_in, const int* in_sizes, int n_in,
                              void* d_out, int out_size, void* d_ws, size_t ws_size,
                              hipStream_t stream) {
    const float* x  = (const float*)d_in[0];
    const float* pw = (const float*)d_in[1];
    const float* pb = (const float*)d_in[2];
    const float* rw = (const float*)d_in[3];
    const float* rb = (const float*)d_in[4];
    const float* ow = (const float*)d_in[5];
    const float* ob = (const float*)d_in[6];
    float* out = (float*)d_out;

    float* ev   = (float*)d_ws;
    float* wp   = ev + EV_FLOATS;
    float* bias = wp + 4096;

    // Zero padded evident (halo must be 0 for SAME conv; ws is poisoned 0xAA)
    hipMemsetAsync(ev, 0, (size_t)EV_FLOATS * sizeof(float), stream);
    repack_w<<<16, 256, 0, stream>>>(pw, pb, rw, rb, ow, ob, wp, bias);
    conv1x1_k<<<512, 256, 0, stream>>>(x, wp, bias, ev, out);
    hough_k<<<1024, 256, 0, stream>>>(ev, out);
}

// Round 2
// 468.942 us; speedup vs baseline: 1.0041x; 1.0041x over previous
//
#include <hip/hip_runtime.h>
#include <math.h>

// Problem constants
#define BB   2
#define CC   256
#define HH   256
#define WW   512
#define HW   (HH*WW)        // 131072
#define IMG  (CC*HW)        // per-batch x block

// Padded evident layout: [B][13][HP][WP] of bf16 (ushort), 16-halo of zeros
#define HP   (HH+32)        // 288
#define WP   (WW+32)        // 544
#define CHP  (HP*WP)        // 156672 elements per channel plane
#define EVB  (13*CHP)       // per-batch evident block
#define EV_ELEMS (BB*EVB)   // 4073472 ushorts = 8.15 MB

// Output layout (flat concat): x_cls [2,1,256,512] | x_reg [2,1,256,512] | x_off [2,2,256,512]
#define OUT_REG (BB*HW)     // 262144
#define OUT_OFF (2*BB*HW)   // 524288

static __device__ __forceinline__ unsigned short f2bf_rn(float f) {
    unsigned int u = __float_as_uint(f);
    u += 0x7fffu + ((u >> 16) & 1u);   // round-to-nearest-even
    return (unsigned short)(u >> 16);
}

// ---------------------------------------------------------------------------
// Repack weights into wp[c][16] (c-major, 16 contiguous output channels) and
// pack 16 biases, so the main kernel can bulk-load them.
__global__ void repack_w(const float* __restrict__ pw, const float* __restrict__ pb,
                         const float* __restrict__ rw, const float* __restrict__ rb,
                         const float* __restrict__ ow, const float* __restrict__ ob,
                         float* __restrict__ wp, float* __restrict__ bias) {
    int i = blockIdx.x * blockDim.x + threadIdx.x;
    if (i < 4096) {
        int c = i >> 4, o = i & 15;
        float v;
        if (o < 13)       v = pw[o * CC + c];
        else if (o == 13) v = rw[c];
        else              v = ow[(o - 14) * CC + c];
        wp[c * 16 + o] = v;
    }
    if (i < 16) {
        float v = (i < 13) ? pb[i] : (i == 13 ? rb[0] : ob[i - 14]);
        bias[i] = v;
    }
}

// ---------------------------------------------------------------------------
// Fused 1x1 convs: 16 output channels per pixel, 2 px/thread (float2 loads).
// Weights staged in LDS (16 KB) -> uniform broadcast ds_read_b128, which caps
// the worst case if global uniform loads don't scalarize to s_load.
// Channels 0..12 -> relu -> bf16 padded evident; 13 -> x_reg; 14,15 -> x_off.
__global__ __launch_bounds__(256) void conv1x1_k(
    const float* __restrict__ x, const float* __restrict__ wp,
    const float* __restrict__ bias, unsigned short* __restrict__ ev,
    float* __restrict__ out) {
    __shared__ float4 wlds[1024];            // [c][4] = 4096 floats
    int tid = threadIdx.x;
    const float4* wp4 = (const float4*)wp;
#pragma unroll
    for (int j = 0; j < 4; j++) wlds[tid + j * 256] = wp4[tid + j * 256];
    __syncthreads();

    int g  = blockIdx.x * 256 + tid;         // 131072 threads
    int p  = g * 2;
    int b  = p >> 17;
    int hw = p & (HW - 1);
    const float* xb = x + (size_t)b * IMG + hw;

    float acc0[16], acc1[16];
#pragma unroll
    for (int o = 0; o < 16; o++) { acc0[o] = 0.f; acc1[o] = 0.f; }

#pragma unroll 2
    for (int c = 0; c < CC; c++) {
        float2 v = *(const float2*)(xb + c * HW);
        float4 w[4];
#pragma unroll
        for (int j = 0; j < 4; j++) w[j] = wlds[c * 4 + j];
        const float* wf = (const float*)w;
#pragma unroll
        for (int o = 0; o < 16; o++) {
            float wv = wf[o];
            acc0[o] = fmaf(v.x, wv, acc0[o]);
            acc1[o] = fmaf(v.y, wv, acc1[o]);
        }
    }

    int y0 = hw >> 9, x0 = hw & 511;         // px pair is always within one row
    unsigned short* evb = ev + (size_t)b * EVB;
    unsigned int* evrow;
#pragma unroll
    for (int o = 0; o < 13; o++) {
        float bo = bias[o];
        float e0 = fmaxf(acc0[o] + bo, 0.f);
        float e1 = fmaxf(acc1[o] + bo, 0.f);
        unsigned int pack = (unsigned int)f2bf_rn(e0) | ((unsigned int)f2bf_rn(e1) << 16);
        evrow = (unsigned int*)(evb + o * CHP + (y0 + 16) * WP + (x0 + 16));
        *evrow = pack;                        // 4B-aligned: WP even, x0 even
    }
    float rbv = bias[13];
    *(float2*)(out + OUT_REG + b * HW + hw) = make_float2(acc0[13] + rbv, acc1[13] + rbv);
#pragma unroll
    for (int o = 14; o < 16; o++) {
        float bo = bias[o];
        *(float2*)(out + OUT_OFF + b * 2 * HW + (o - 14) * HW + hw) =
            make_float2(acc0[o] + bo, acc1[o] + bo);
    }
}

// ---------------------------------------------------------------------------
// Hough vote conv (33x33, 13 regions) + sigmoid, reading bf16 evident.
// Per-tap (offset, weight) fused into one int2 -> single ds_read_b64.
// XCD-aware swizzle: blocks with bid%8==k (presumed XCD k) cover a contiguous
// 64-row span, so each XCD's gather working set (~1.4 MB) fits its 4 MiB L2.
__global__ __launch_bounds__(256) void hough_k(const unsigned short* __restrict__ ev,
                                               float* __restrict__ out) {
    __shared__ int2 tab[1089];
    __shared__ int  cnt[13];
    int tid = threadIdx.x;
    if (tid < 13) cnt[tid] = 0;
    __syncthreads();

    for (int i = tid; i < 1089; i += 256) {
        int ky = i / 33, kx = i - ky * 33;
        int ys = 16 - ky, xs = 16 - kx;       // filter-source coords (flip folded in)
        int r2 = ys * ys + xs * xs;
        int bin;
        if (ys == 0)     bin = (xs >= 0) ? 0 : 2;
        else if (ys > 0) bin = (xs > 0) ? 0 : 1;
        else             bin = (xs < 0) ? 2 : 3;
        int c;
        if (r2 <= 4)        c = 0;
        else if (r2 <= 64)  c = 1 + bin;
        else if (r2 <= 256) c = 5 + bin;
        else                c = 9 + bin;
        tab[i].x = c;                          // temp: region id
        atomicAdd(&cnt[c], 1);
    }
    __syncthreads();

    for (int i = tid; i < 1089; i += 256) {
        int ky = i / 33, kx = i - ky * 33;
        int c  = tab[i].x;
        float w = 1.0f / (float)cnt[c];
        tab[i] = make_int2(c * CHP + (ky - 16) * WP + (kx - 16), __float_as_int(w));
    }
    __syncthreads();

    int bid = blockIdx.x;                      // 1024 blocks
    int sb  = (bid & 7) * 128 + (bid >> 3);    // XCD-contiguous pixel-block id
    int p   = sb * 256 + tid;
    int b   = p >> 17;
    int hw  = p & (HW - 1);
    int y   = hw >> 9, xx = hw & 511;
    const unsigned short* pc = ev + (size_t)b * EVB + (y + 16) * WP + (xx + 16);

    float s = 0.f;
#pragma unroll 8
    for (int t = 0; t < 1089; t++) {
        int2 e = tab[t];
        float f = __uint_as_float(((unsigned int)pc[e.x]) << 16);  // bf16 -> f32
        s = fmaf(f, __int_as_float(e.y), s);
    }
    float cls = 1.0f / (1.0f + expf(-s));
    out[b * HW + hw] = cls;
}

// ---------------------------------------------------------------------------
extern "C" void kernel_launch(void* const* d_in, const int* in_sizes, int n_in,
                              void* d_out, int out_size, void* d_ws, size_t ws_size,
                              hipStream_t stream) {
    const float* x  = (const float*)d_in[0];
    const float* pw = (const float*)d_in[1];
    const float* pb = (const float*)d_in[2];
    const float* rw = (const float*)d_in[3];
    const float* rb = (const float*)d_in[4];
    const float* ow = (const float*)d_in[5];
    const float* ob = (const float*)d_in[6];
    float* out = (float*)d_out;

    unsigned short* ev = (unsigned short*)d_ws;
    float* wp   = (float*)(ev + EV_ELEMS);     // byte offset 8146944, 16B-aligned
    float* bias = wp + 4096;

    // Zero padded evident halo (ws is poisoned 0xAA before every launch)
    hipMemsetAsync(ev, 0, (size_t)EV_ELEMS * sizeof(unsigned short), stream);
    repack_w<<<16, 256, 0, stream>>>(pw, pb, rw, rb, ow, ob, wp, bias);
    conv1x1_k<<<512, 256, 0, stream>>>(x, wp, bias, ev, out);
    hough_k<<<1024, 256, 0, stream>>>(ev, out);
}

// Round 3
// 411.908 us; speedup vs baseline: 1.1431x; 1.1385x over previous
//
#include <hip/hip_runtime.h>
#include <math.h>

// Problem constants
#define BB   2
#define CC   256
#define HH   256
#define WW   512
#define HW   (HH*WW)        // 131072
#define IMG  (CC*HW)        // per-batch x block

// Padded evident/prefix layout: [B][13][HPP][WPP] fp32.
// Interior rows 16..271, interior cols 18..529 (left pad 18 so off_lo >= 0,
// right pad 16). After prefix_k each row holds its inclusive prefix sum.
#define HPP  288
#define WPP  546
#define CHPP (HPP*WPP)      // 157248
#define EVB2 (13*CHPP)      // 2044224 per batch
#define EV2_FLOATS (BB*EVB2) // 4088448 floats = 16.35 MB

// Output layout (flat concat): x_cls [2,1,256,512] | x_reg [2,1,256,512] | x_off [2,2,256,512]
#define OUT_REG (BB*HW)     // 262144
#define OUT_OFF (2*BB*HW)   // 524288

// Log-polar region id for filter-source coords (flip already folded in by caller)
static __device__ __forceinline__ int region_of(int ys, int xs) {
    int r2 = ys * ys + xs * xs;
    int bin;
    if (ys == 0)     bin = (xs >= 0) ? 0 : 2;
    else if (ys > 0) bin = (xs > 0) ? 0 : 1;
    else             bin = (xs < 0) ? 2 : 3;
    if (r2 <= 4)   return 0;
    if (r2 <= 64)  return 1 + bin;
    if (r2 <= 256) return 5 + bin;
    return 9 + bin;
}

// ---------------------------------------------------------------------------
// Repack weights into wp[c][16] (c-major) + 16 packed biases.
__global__ void repack_w(const float* __restrict__ pw, const float* __restrict__ pb,
                         const float* __restrict__ rw, const float* __restrict__ rb,
                         const float* __restrict__ ow, const float* __restrict__ ob,
                         float* __restrict__ wp, float* __restrict__ bias) {
    int i = blockIdx.x * blockDim.x + threadIdx.x;
    if (i < 4096) {
        int c = i >> 4, o = i & 15;
        float v;
        if (o < 13)       v = pw[o * CC + c];
        else if (o == 13) v = rw[c];
        else              v = ow[(o - 14) * CC + c];
        wp[c * 16 + o] = v;
    }
    if (i < 16) {
        float v = (i < 13) ? pb[i] : (i == 13 ? rb[0] : ob[i - 14]);
        bias[i] = v;
    }
}

// ---------------------------------------------------------------------------
// Fused 1x1 convs, 1 px/thread (1024 blocks -> 4 waves/SIMD for latency hiding).
// Weights broadcast from LDS. Channels 0..12 -> relu -> padded fp32 evident;
// 13 -> x_reg; 14,15 -> x_off.
__global__ __launch_bounds__(256) void conv1x1_k(
    const float* __restrict__ x, const float* __restrict__ wp,
    const float* __restrict__ bias, float* __restrict__ ev,
    float* __restrict__ out) {
    __shared__ float4 wlds[1024];            // [c][4] = 4096 floats
    int tid = threadIdx.x;
    const float4* wp4 = (const float4*)wp;
#pragma unroll
    for (int j = 0; j < 4; j++) wlds[tid + j * 256] = wp4[tid + j * 256];
    __syncthreads();

    int g  = blockIdx.x * 256 + tid;         // 262144 threads
    int b  = g >> 17;
    int hw = g & (HW - 1);
    const float* xb = x + (size_t)b * IMG + hw;

    float acc[16];
#pragma unroll
    for (int o = 0; o < 16; o++) acc[o] = 0.f;

#pragma unroll 4
    for (int c = 0; c < CC; c++) {
        float v = xb[c * HW];
        float4 w[4];
#pragma unroll
        for (int j = 0; j < 4; j++) w[j] = wlds[c * 4 + j];
        const float* wf = (const float*)w;
#pragma unroll
        for (int o = 0; o < 16; o++) acc[o] = fmaf(v, wf[o], acc[o]);
    }

    int y0 = hw >> 9, x0 = hw & 511;
    float* evb = ev + (size_t)b * EVB2 + (y0 + 16) * WPP + (x0 + 18);
#pragma unroll
    for (int o = 0; o < 13; o++) {
        evb[o * CHPP] = fmaxf(acc[o] + bias[o], 0.f);
    }
    out[OUT_REG + b * HW + hw] = acc[13] + bias[13];
    out[OUT_OFF + b * 2 * HW + hw]      = acc[14] + bias[14];
    out[OUT_OFF + b * 2 * HW + HW + hw] = acc[15] + bias[15];
}

// ---------------------------------------------------------------------------
// In-place row-wise inclusive prefix sum over padded evident.
// One wave per row (7488 rows), 9 segments of 64 with wave-scan + carry.
__global__ __launch_bounds__(256) void prefix_k(float* __restrict__ ev) {
    int row  = blockIdx.x * 4 + (threadIdx.x >> 6);
    int lane = threadIdx.x & 63;
    if (row >= BB * 13 * HPP) return;
    float* r = ev + (size_t)row * WPP;
    float carry = 0.f;
    for (int seg = 0; seg < WPP; seg += 64) {
        int i = seg + lane;
        float v = (i < WPP) ? r[i] : 0.f;
#pragma unroll
        for (int d = 1; d < 64; d <<= 1) {
            float t = __shfl_up(v, d, 64);
            if (lane >= d) v += t;
        }
        v += carry;
        if (i < WPP) r[i] = v;
        carry = __shfl(v, 63, 64);
    }
}

// ---------------------------------------------------------------------------
// Hough vote conv via run-length decomposition on row prefix sums + sigmoid.
// Filter is piecewise-constant over 13 regions -> each of the 33 filter rows
// is ~5-9 constant-channel runs; each run = P[hi] - P[lo] (2 loads, 2 FMAs).
// ~594 table entries instead of 1089 taps. XCD swizzle keeps each XCD's
// gather slab (~2.7 MB) inside its private L2.
__global__ __launch_bounds__(256) void hough_k(const float* __restrict__ P,
                                               float* __restrict__ out) {
    __shared__ int  cnt[13];
    __shared__ int  runbuf[33 * 16];
    __shared__ int  countrow[33];
    __shared__ int  rowstart[34];
    __shared__ int2 tab[608];
    int tid = threadIdx.x;
    if (tid < 13) cnt[tid] = 0;
    __syncthreads();

    // Phase A: region pixel counts (for 1/count weights)
    for (int i = tid; i < 1089; i += 256) {
        int ky = i / 33, kx = i - ky * 33;
        atomicAdd(&cnt[region_of(16 - ky, 16 - kx)], 1);
    }
    __syncthreads();

    // Phase B: per filter row, find constant-channel runs
    if (tid < 33) {
        int ky = tid, n = 0;
        int c0 = region_of(16 - ky, 16);     // kx = 0
        int kxa = 0;
        for (int kx = 1; kx <= 33; kx++) {
            int c = (kx < 33) ? region_of(16 - ky, 16 - kx) : -1;
            if (c != c0) {
                runbuf[tid * 16 + n] = c0 | (kxa << 4) | ((kx - 1) << 10);
                n++;
                c0 = c; kxa = kx;
            }
        }
        countrow[tid] = n;
    }
    __syncthreads();

    // Phase C: compact offsets
    if (tid == 0) {
        int a = 0;
        for (int t = 0; t < 33; t++) { rowstart[t] = a; a += countrow[t]; }
        rowstart[33] = a;
    }
    __syncthreads();

    // Phase D: emit (offset, +/-w) entry pairs
    if (tid < 33) {
        int ky = tid, base = rowstart[tid], n = countrow[tid];
        for (int j = 0; j < n; j++) {
            int rn  = runbuf[tid * 16 + j];
            int c   = rn & 15, kxa = (rn >> 4) & 63, kxb = (rn >> 10) & 63;
            float w = 1.0f / (float)cnt[c];
            int off0 = c * CHPP + (ky - 16) * WPP;
            tab[2 * (base + j)]     = make_int2(off0 + (kxb - 16), __float_as_int(w));
            tab[2 * (base + j) + 1] = make_int2(off0 + (kxa - 17), __float_as_int(-w));
        }
    }
    __syncthreads();
    int m = 2 * rowstart[33];

    // Pixel gather
    int bid = blockIdx.x;                      // 1024 blocks
    int sb  = (bid & 7) * 128 + (bid >> 3);    // XCD-contiguous pixel-block id
    int p   = sb * 256 + tid;
    int b   = p >> 17;
    int hw  = p & (HW - 1);
    int y   = hw >> 9, xx = hw & 511;
    const float* Pb = P + (size_t)b * EVB2 + (y + 16) * WPP + (xx + 18);

    float s = 0.f;
#pragma unroll 4
    for (int t = 0; t < m; t++) {
        int2 e = tab[t];
        s = fmaf(Pb[e.x], __int_as_float(e.y), s);
    }
    out[b * HW + hw] = 1.0f / (1.0f + expf(-s));
}

// ---------------------------------------------------------------------------
extern "C" void kernel_launch(void* const* d_in, const int* in_sizes, int n_in,
                              void* d_out, int out_size, void* d_ws, size_t ws_size,
                              hipStream_t stream) {
    const float* x  = (const float*)d_in[0];
    const float* pw = (const float*)d_in[1];
    const float* pb = (const float*)d_in[2];
    const float* rw = (const float*)d_in[3];
    const float* rb = (const float*)d_in[4];
    const float* ow = (const float*)d_in[5];
    const float* ob = (const float*)d_in[6];
    float* out = (float*)d_out;

    float* ev   = (float*)d_ws;
    float* wp   = ev + EV2_FLOATS;
    float* bias = wp + 4096;

    // Zero padded evident (halo must be 0; ws is poisoned 0xAA each launch)
    hipMemsetAsync(ev, 0, (size_t)EV2_FLOATS * sizeof(float), stream);
    repack_w<<<16, 256, 0, stream>>>(pw, pb, rw, rb, ow, ob, wp, bias);
    conv1x1_k<<<1024, 256, 0, stream>>>(x, wp, bias, ev, out);
    prefix_k<<<1872, 256, 0, stream>>>(ev);
    hough_k<<<1024, 256, 0, stream>>>(ev, out);
}

// Round 4
// 402.175 us; speedup vs baseline: 1.1708x; 1.0242x over previous
//
#include <hip/hip_runtime.h>
#include <math.h>

// Problem constants
#define BB   2
#define CC   256
#define HH   256
#define WW   512
#define HW   (HH*WW)        // 131072
#define IMG  (CC*HW)        // per-batch x block

// Padded evident/prefix layout: [B][13][HPP][WPP] fp32.
// Interior rows 16..271, interior cols 18..529 (left pad 18 so off_lo >= 0).
#define HPP  288
#define WPP  546
#define CHPP (HPP*WPP)      // 157248
#define EVB2 (13*CHPP)      // 2044224 per batch
#define EV2_FLOATS (BB*EVB2) // 4088448 floats = 16.35 MB

// Output layout (flat concat): x_cls | x_reg | x_off
#define OUT_REG (BB*HW)     // 262144
#define OUT_OFF (2*BB*HW)   // 524288

// Log-polar region id for filter-source coords (flip folded in by caller)
static __device__ __forceinline__ int region_of(int ys, int xs) {
    int r2 = ys * ys + xs * xs;
    int bin;
    if (ys == 0)     bin = (xs >= 0) ? 0 : 2;
    else if (ys > 0) bin = (xs > 0) ? 0 : 1;
    else             bin = (xs < 0) ? 2 : 3;
    if (r2 <= 4)   return 0;
    if (r2 <= 64)  return 1 + bin;
    if (r2 <= 256) return 5 + bin;
    return 9 + bin;
}

// ---------------------------------------------------------------------------
// setup_k: blocks 0..15 repack weights into wp[c][16] + 16 biases;
// block 16 builds the run-length vote table (offset, +/-weight) in GLOBAL
// memory once (was: rebuilt in LDS by every hough block).
__global__ void setup_k(const float* __restrict__ pw, const float* __restrict__ pb,
                        const float* __restrict__ rw, const float* __restrict__ rb,
                        const float* __restrict__ ow, const float* __restrict__ ob,
                        float* __restrict__ wp, float* __restrict__ bias,
                        int2* __restrict__ tabg, int* __restrict__ mg) {
    int blk = blockIdx.x, tid = threadIdx.x;
    if (blk < 16) {
        int i = blk * 256 + tid;
        int c = i >> 4, o = i & 15;
        float v;
        if (o < 13)       v = pw[o * CC + c];
        else if (o == 13) v = rw[c];
        else              v = ow[(o - 14) * CC + c];
        wp[c * 16 + o] = v;
        if (i < 16) {
            float bv = (i < 13) ? pb[i] : (i == 13 ? rb[0] : ob[i - 14]);
            bias[i] = bv;
        }
    } else {
        __shared__ int cnt[13];
        __shared__ int runbuf[33 * 16];
        __shared__ int countrow[33];
        __shared__ int rowstart[34];
        if (tid < 13) cnt[tid] = 0;
        __syncthreads();
        for (int i = tid; i < 1089; i += 256) {
            int ky = i / 33, kx = i - ky * 33;
            atomicAdd(&cnt[region_of(16 - ky, 16 - kx)], 1);
        }
        __syncthreads();
        if (tid < 33) {
            int ky = tid, n = 0;
            int c0 = region_of(16 - ky, 16);
            int kxa = 0;
            for (int kx = 1; kx <= 33; kx++) {
                int c = (kx < 33) ? region_of(16 - ky, 16 - kx) : -1;
                if (c != c0) {
                    runbuf[tid * 16 + n] = c0 | (kxa << 4) | ((kx - 1) << 10);
                    n++;
                    c0 = c; kxa = kx;
                }
            }
            countrow[tid] = n;
        }
        __syncthreads();
        if (tid == 0) {
            int a = 0;
            for (int t = 0; t < 33; t++) { rowstart[t] = a; a += countrow[t]; }
            rowstart[33] = a;
            mg[0] = 2 * a;
        }
        __syncthreads();
        if (tid < 33) {
            int ky = tid, base = rowstart[tid], n = countrow[tid];
            for (int j = 0; j < n; j++) {
                int rn  = runbuf[tid * 16 + j];
                int c   = rn & 15, kxa = (rn >> 4) & 63, kxb = (rn >> 10) & 63;
                float w = 1.0f / (float)cnt[c];
                int off0 = c * CHPP + (ky - 16) * WPP;
                tabg[2 * (base + j)]     = make_int2(off0 + (kxb - 16), __float_as_int(w));
                tabg[2 * (base + j) + 1] = make_int2(off0 + (kxa - 17), __float_as_int(-w));
            }
        }
    }
}

// ---------------------------------------------------------------------------
// Fused 1x1 convs, 2 px/thread (float2 coalesced), 512 blocks.
// Weights read straight from global with wave-uniform address -> expect
// s_load_dwordx16 on the scalar pipe (no LDS, no VMEM broadcast).
__global__ __launch_bounds__(256) void conv1x1_k(
    const float* __restrict__ x, const float* __restrict__ wp,
    const float* __restrict__ bias, float* __restrict__ ev,
    float* __restrict__ out) {
    int tid = threadIdx.x;
    int g  = blockIdx.x * 256 + tid;         // 131072 threads
    int p  = g * 2;
    int b  = p >> 17;
    int hw = p & (HW - 1);
    const float* xb = x + (size_t)b * IMG + hw;

    float acc0[16], acc1[16];
#pragma unroll
    for (int o = 0; o < 16; o++) { acc0[o] = 0.f; acc1[o] = 0.f; }

#pragma unroll 4
    for (int c = 0; c < CC; c++) {
        float2 v = *(const float2*)(xb + c * HW);
        const float* wr = wp + c * 16;       // uniform address -> s_load
#pragma unroll
        for (int o = 0; o < 16; o++) {
            float wv = wr[o];
            acc0[o] = fmaf(v.x, wv, acc0[o]);
            acc1[o] = fmaf(v.y, wv, acc1[o]);
        }
    }

    int y0 = hw >> 9, x0 = hw & 511;         // px pair within one row
    float* evb = ev + (size_t)b * EVB2 + (y0 + 16) * WPP + (x0 + 18);
#pragma unroll
    for (int o = 0; o < 13; o++) {
        float bo = bias[o];
        *(float2*)(evb + o * CHPP) =
            make_float2(fmaxf(acc0[o] + bo, 0.f), fmaxf(acc1[o] + bo, 0.f));
    }
    float rbv = bias[13];
    *(float2*)(out + OUT_REG + b * HW + hw) = make_float2(acc0[13] + rbv, acc1[13] + rbv);
#pragma unroll
    for (int o = 14; o < 16; o++) {
        float bo = bias[o];
        *(float2*)(out + OUT_OFF + b * 2 * HW + (o - 14) * HW + hw) =
            make_float2(acc0[o] + bo, acc1[o] + bo);
    }
}

// ---------------------------------------------------------------------------
// In-place row-wise inclusive prefix sum over the 6656 INTERIOR rows only
// (halo rows are zero from the memset; prefix of zeros is zeros).
__global__ __launch_bounds__(256) void prefix_k(float* __restrict__ ev) {
    int r    = blockIdx.x * 4 + (threadIdx.x >> 6);
    int lane = threadIdx.x & 63;
    if (r >= BB * 13 * HH) return;
    int b   = r / (13 * HH);
    int rem = r - b * (13 * HH);
    int ch  = rem >> 8;
    int y   = rem & 255;
    float* row = ev + (size_t)(b * 13 + ch) * CHPP + (size_t)(y + 16) * WPP;
    float carry = 0.f;
    for (int seg = 0; seg < WPP; seg += 64) {
        int i = seg + lane;
        float v = (i < WPP) ? row[i] : 0.f;
#pragma unroll
        for (int d = 1; d < 64; d <<= 1) {
            float t = __shfl_up(v, d, 64);
            if (lane >= d) v += t;
        }
        v += carry;
        if (i < WPP) row[i] = v;
        carry = __shfl(v, 63, 64);
    }
}

// ---------------------------------------------------------------------------
// Hough vote conv via run boundaries on row prefix sums + sigmoid.
// Table entries read from global with uniform address -> s_load on the
// scalar pipe; pixel loop is then 1 vector load + 1 FMA per entry.
// XCD swizzle keeps each XCD's gather slab (~2.7 MB) inside its 4 MiB L2.
__global__ __launch_bounds__(256) void hough_k(const float* __restrict__ P,
                                               const int2* __restrict__ tabg,
                                               const int* __restrict__ mg,
                                               float* __restrict__ out) {
    int m   = mg[0];
    int tid = threadIdx.x;
    int bid = blockIdx.x;                      // 1024 blocks
    int sb  = (bid & 7) * 128 + (bid >> 3);    // XCD-contiguous pixel-block id
    int p   = sb * 256 + tid;
    int b   = p >> 17;
    int hw  = p & (HW - 1);
    int y   = hw >> 9, xx = hw & 511;
    const float* Pb = P + (size_t)b * EVB2 + (y + 16) * WPP + (xx + 18);

    float s = 0.f;
#pragma unroll 8
    for (int t = 0; t < m; t++) {
        int2 e = tabg[t];                      // uniform -> scalar load
        s = fmaf(Pb[e.x], __int_as_float(e.y), s);
    }
    out[b * HW + hw] = 1.0f / (1.0f + expf(-s));
}

// ---------------------------------------------------------------------------
extern "C" void kernel_launch(void* const* d_in, const int* in_sizes, int n_in,
                              void* d_out, int out_size, void* d_ws, size_t ws_size,
                              hipStream_t stream) {
    const float* x  = (const float*)d_in[0];
    const float* pw = (const float*)d_in[1];
    const float* pb = (const float*)d_in[2];
    const float* rw = (const float*)d_in[3];
    const float* rb = (const float*)d_in[4];
    const float* ow = (const float*)d_in[5];
    const float* ob = (const float*)d_in[6];
    float* out = (float*)d_out;

    float* ev   = (float*)d_ws;
    float* wp   = ev + EV2_FLOATS;
    float* bias = wp + 4096;
    int2*  tabg = (int2*)(bias + 16);          // 8B-aligned (even float offset)
    int*   mg   = (int*)(tabg + 2048);

    // Zero padded evident (halo must be 0; ws is poisoned 0xAA each launch)
    hipMemsetAsync(ev, 0, (size_t)EV2_FLOATS * sizeof(float), stream);
    setup_k<<<17, 256, 0, stream>>>(pw, pb, rw, rb, ow, ob, wp, bias, tabg, mg);
    conv1x1_k<<<512, 256, 0, stream>>>(x, wp, bias, ev, out);
    prefix_k<<<1664, 256, 0, stream>>>(ev);
    hough_k<<<1024, 256, 0, stream>>>(ev, tabg, mg, out);
}

// Round 5
// 397.518 us; speedup vs baseline: 1.1845x; 1.0117x over previous
//
#include <hip/hip_runtime.h>
#include <math.h>

// Problem constants
#define BB   2
#define CC   256
#define HH   256
#define WW   512
#define HW   (HH*WW)        // 131072
#define IMG  (CC*HW)        // per-batch x block

// Padded prefix layout: [B][13][HPP][WPP] fp32.
// Interior rows 16..271; cols: 0..17 left pad (zeros), 18..529 interior
// inclusive row-prefix, 530..545 right pad (= row total).
#define HPP  288
#define WPP  546
#define CHPP (HPP*WPP)      // 157248
#define EVB2 (13*CHPP)      // 2044224 per batch
#define EV2_FLOATS (BB*EVB2) // 4088448 floats = 16.35 MB

// Output layout (flat concat): x_cls | x_reg | x_off
#define OUT_REG (BB*HW)     // 262144
#define OUT_OFF (2*BB*HW)   // 524288

// Log-polar region id for filter-source coords (flip folded in by caller)
static __device__ __forceinline__ int region_of(int ys, int xs) {
    int r2 = ys * ys + xs * xs;
    int bin;
    if (ys == 0)     bin = (xs >= 0) ? 0 : 2;
    else if (ys > 0) bin = (xs > 0) ? 0 : 1;
    else             bin = (xs < 0) ? 2 : 3;
    if (r2 <= 4)   return 0;
    if (r2 <= 64)  return 1 + bin;
    if (r2 <= 256) return 5 + bin;
    return 9 + bin;
}

// ---------------------------------------------------------------------------
// setup_k: blocks 0..15 repack weights wp[c][16] + 16 biases; block 16 builds
// the run-length vote table in global memory; blocks 17..68 zero the 52
// top/bottom halo row-slabs of ev (replaces the 16 MB memset — conv writes
// everything else including left/right pads).
__global__ void setup_k(const float* __restrict__ pw, const float* __restrict__ pb,
                        const float* __restrict__ rw, const float* __restrict__ rb,
                        const float* __restrict__ ow, const float* __restrict__ ob,
                        float* __restrict__ wp, float* __restrict__ bias,
                        int2* __restrict__ tabg, int* __restrict__ mg,
                        float* __restrict__ ev) {
    int blk = blockIdx.x, tid = threadIdx.x;
    if (blk < 16) {
        int i = blk * 256 + tid;
        int c = i >> 4, o = i & 15;
        float v;
        if (o < 13)       v = pw[o * CC + c];
        else if (o == 13) v = rw[c];
        else              v = ow[(o - 14) * CC + c];
        wp[c * 16 + o] = v;
        if (i < 16) {
            float bv = (i < 13) ? pb[i] : (i == 13 ? rb[0] : ob[i - 14]);
            bias[i] = bv;
        }
    } else if (blk == 16) {
        __shared__ int cnt[13];
        __shared__ int runbuf[33 * 16];
        __shared__ int countrow[33];
        __shared__ int rowstart[34];
        if (tid < 13) cnt[tid] = 0;
        __syncthreads();
        for (int i = tid; i < 1089; i += 256) {
            int ky = i / 33, kx = i - ky * 33;
            atomicAdd(&cnt[region_of(16 - ky, 16 - kx)], 1);
        }
        __syncthreads();
        if (tid < 33) {
            int ky = tid, n = 0;
            int c0 = region_of(16 - ky, 16);
            int kxa = 0;
            for (int kx = 1; kx <= 33; kx++) {
                int c = (kx < 33) ? region_of(16 - ky, 16 - kx) : -1;
                if (c != c0) {
                    runbuf[tid * 16 + n] = c0 | (kxa << 4) | ((kx - 1) << 10);
                    n++;
                    c0 = c; kxa = kx;
                }
            }
            countrow[tid] = n;
        }
        __syncthreads();
        if (tid == 0) {
            int a = 0;
            for (int t = 0; t < 33; t++) { rowstart[t] = a; a += countrow[t]; }
            rowstart[33] = a;
            mg[0] = 2 * a;
        }
        __syncthreads();
        if (tid < 33) {
            int ky = tid, base = rowstart[tid], n = countrow[tid];
            for (int j = 0; j < n; j++) {
                int rn  = runbuf[tid * 16 + j];
                int c   = rn & 15, kxa = (rn >> 4) & 63, kxb = (rn >> 10) & 63;
                float w = 1.0f / (float)cnt[c];
                int off0 = c * CHPP + (ky - 16) * WPP;
                tabg[2 * (base + j)]     = make_int2(off0 + (kxb - 16), __float_as_int(w));
                tabg[2 * (base + j) + 1] = make_int2(off0 + (kxa - 17), __float_as_int(-w));
            }
        }
    } else {
        // Zero one 16-row halo slab (16*546 = 8736 floats = 2184 float4)
        int seg   = blk - 17;                 // 0..51
        int plane = seg >> 1;                 // 0..25  (b*13+ch)
        int half  = seg & 1;
        float* base = ev + (size_t)plane * CHPP + (half ? (size_t)272 * WPP : 0);
        float4 z = make_float4(0.f, 0.f, 0.f, 0.f);
        float4* b4 = (float4*)base;           // CHPP, 272*WPP both %4 == 0
#pragma unroll
        for (int it = 0; it < 9; it++) {
            int idx = it * 256 + tid;
            if (idx < 2184) b4[idx] = z;
        }
    }
}

// ---------------------------------------------------------------------------
// Fused 1x1 convs + row prefix scan. One block = one image row (512 px,
// 1 px/thread, 512 threads = 8 waves -> 4 waves/SIMD occupancy).
// Weights via wave-uniform global reads (s_load). Channels 0..12 -> relu ->
// in-block inclusive scan -> prefix written directly (plus left-pad zeros and
// right-pad row totals); 13 -> x_reg; 14,15 -> x_off.
__global__ __launch_bounds__(512) void convscan_k(
    const float* __restrict__ x, const float* __restrict__ wp,
    const float* __restrict__ bias, float* __restrict__ ev,
    float* __restrict__ out) {
    __shared__ float part[13][8];
    int tid  = threadIdx.x;
    int lane = tid & 63;
    int wv   = tid >> 6;
    int bid  = blockIdx.x;                   // 512 blocks = BB*HH rows
    int b    = bid >> 8;
    int y    = bid & 255;
    int hw   = y * WW + tid;
    const float* xb = x + (size_t)b * IMG + hw;

    float acc[16];
#pragma unroll
    for (int o = 0; o < 16; o++) acc[o] = 0.f;

#pragma unroll 4
    for (int c = 0; c < CC; c++) {
        float v = xb[c * HW];
        const float* wr = wp + c * 16;       // uniform -> s_load_dwordx16
#pragma unroll
        for (int o = 0; o < 16; o++) acc[o] = fmaf(v, wr[o], acc[o]);
    }

    // relu+bias, then per-channel wave-inclusive scan; publish wave totals
#pragma unroll
    for (int o = 0; o < 13; o++) {
        float v = fmaxf(acc[o] + bias[o], 0.f);
#pragma unroll
        for (int d = 1; d < 64; d <<= 1) {
            float t = __shfl_up(v, d, 64);
            if (lane >= d) v += t;
        }
        acc[o] = v;
        if (lane == 63) part[o][wv] = v;
    }
    __syncthreads();

    size_t rowbase = (size_t)(b * 13) * CHPP + (size_t)(y + 16) * WPP;
#pragma unroll
    for (int o = 0; o < 13; o++) {
        float off = 0.f;
#pragma unroll
        for (int w2 = 0; w2 < 7; w2++)
            if (w2 < wv) off += part[o][w2];
        ev[rowbase + o * CHPP + 18 + tid] = acc[o] + off;
    }
    // left pad zeros (cols 0..17, 13 channels = 234 stores)
    if (tid < 234) {
        int o = tid / 18, j = tid - o * 18;
        ev[rowbase + o * CHPP + j] = 0.f;
    }
    // right pad = row total (cols 530..545, 13 channels = 208 stores)
    if (tid < 208) {
        int o = tid >> 4, j = tid & 15;
        float tot = 0.f;
#pragma unroll
        for (int w2 = 0; w2 < 8; w2++) tot += part[o][w2];
        ev[rowbase + o * CHPP + 530 + j] = tot;
    }

    out[OUT_REG + b * HW + hw]          = acc[13] + bias[13];
    out[OUT_OFF + b * 2 * HW + hw]      = acc[14] + bias[14];
    out[OUT_OFF + b * 2 * HW + HW + hw] = acc[15] + bias[15];
}

// ---------------------------------------------------------------------------
// Hough vote conv via run boundaries on row prefix sums + sigmoid.
// Table entries via uniform scalar loads; 1 vector load + 1 FMA per entry.
// XCD swizzle keeps each XCD's gather slab (~2.7 MB) inside its 4 MiB L2.
__global__ __launch_bounds__(256) void hough_k(const float* __restrict__ P,
                                               const int2* __restrict__ tabg,
                                               const int* __restrict__ mg,
                                               float* __restrict__ out) {
    int m   = mg[0];
    int tid = threadIdx.x;
    int bid = blockIdx.x;                      // 1024 blocks
    int sb  = (bid & 7) * 128 + (bid >> 3);    // XCD-contiguous pixel-block id
    int p   = sb * 256 + tid;
    int b   = p >> 17;
    int hw  = p & (HW - 1);
    int y   = hw >> 9, xx = hw & 511;
    const float* Pb = P + (size_t)b * EVB2 + (y + 16) * WPP + (xx + 18);

    float s = 0.f;
#pragma unroll 8
    for (int t = 0; t < m; t++) {
        int2 e = tabg[t];                      // uniform -> scalar load
        s = fmaf(Pb[e.x], __int_as_float(e.y), s);
    }
    out[b * HW + hw] = 1.0f / (1.0f + expf(-s));
}

// ---------------------------------------------------------------------------
extern "C" void kernel_launch(void* const* d_in, const int* in_sizes, int n_in,
                              void* d_out, int out_size, void* d_ws, size_t ws_size,
                              hipStream_t stream) {
    const float* x  = (const float*)d_in[0];
    const float* pw = (const float*)d_in[1];
    const float* pb = (const float*)d_in[2];
    const float* rw = (const float*)d_in[3];
    const float* rb = (const float*)d_in[4];
    const float* ow = (const float*)d_in[5];
    const float* ob = (const float*)d_in[6];
    float* out = (float*)d_out;

    float* ev   = (float*)d_ws;
    float* wp   = ev + EV2_FLOATS;
    float* bias = wp + 4096;
    int2*  tabg = (int2*)(bias + 16);          // 8B-aligned (even float offset)
    int*   mg   = (int*)(tabg + 2048);

    setup_k<<<69, 256, 0, stream>>>(pw, pb, rw, rb, ow, ob, wp, bias, tabg, mg, ev);
    convscan_k<<<512, 512, 0, stream>>>(x, wp, bias, ev, out);
    hough_k<<<1024, 256, 0, stream>>>(ev, tabg, mg, out);
}

// Round 6
// 395.387 us; speedup vs baseline: 1.1909x; 1.0054x over previous
//
#include <hip/hip_runtime.h>
#include <math.h>

// Problem constants
#define BB   2
#define CC   256
#define HH   256
#define WW   512
#define HW   (HH*WW)        // 131072
#define IMG  (CC*HW)        // per-batch x block

// Padded prefix layout: [B][13][HPP][WPP] fp32.
// Interior rows 16..271; cols: 0..17 left pad (zeros), 18..529 interior
// inclusive row-prefix, 530..545 right pad (= row total).
#define HPP  288
#define WPP  546
#define CHPP (HPP*WPP)      // 157248
#define EVB2 (13*CHPP)      // 2044224 per batch
#define EV2_FLOATS (BB*EVB2) // 4088448 floats = 16.35 MB

// Output layout (flat concat): x_cls | x_reg | x_off
#define OUT_REG (BB*HW)     // 262144
#define OUT_OFF (2*BB*HW)   // 524288

// Log-polar region id for filter-source coords (flip folded in by caller)
static __device__ __forceinline__ int region_of(int ys, int xs) {
    int r2 = ys * ys + xs * xs;
    int bin;
    if (ys == 0)     bin = (xs >= 0) ? 0 : 2;
    else if (ys > 0) bin = (xs > 0) ? 0 : 1;
    else             bin = (xs < 0) ? 2 : 3;
    if (r2 <= 4)   return 0;
    if (r2 <= 64)  return 1 + bin;
    if (r2 <= 256) return 5 + bin;
    return 9 + bin;
}

// ---------------------------------------------------------------------------
// setup_k: blocks 0..15 repack weights wp[c][16] + 16 biases; block 16 builds
// the run-length vote table in global memory; blocks 17..68 zero the 52
// top/bottom halo row-slabs of ev (conv writes everything else, incl. pads).
__global__ void setup_k(const float* __restrict__ pw, const float* __restrict__ pb,
                        const float* __restrict__ rw, const float* __restrict__ rb,
                        const float* __restrict__ ow, const float* __restrict__ ob,
                        float* __restrict__ wp, float* __restrict__ bias,
                        int2* __restrict__ tabg, int* __restrict__ mg,
                        float* __restrict__ ev) {
    int blk = blockIdx.x, tid = threadIdx.x;
    if (blk < 16) {
        int i = blk * 256 + tid;
        int c = i >> 4, o = i & 15;
        float v;
        if (o < 13)       v = pw[o * CC + c];
        else if (o == 13) v = rw[c];
        else              v = ow[(o - 14) * CC + c];
        wp[c * 16 + o] = v;
        if (i < 16) {
            float bv = (i < 13) ? pb[i] : (i == 13 ? rb[0] : ob[i - 14]);
            bias[i] = bv;
        }
    } else if (blk == 16) {
        __shared__ int cnt[13];
        __shared__ int runbuf[33 * 16];
        __shared__ int countrow[33];
        __shared__ int rowstart[34];
        if (tid < 13) cnt[tid] = 0;
        __syncthreads();
        for (int i = tid; i < 1089; i += 256) {
            int ky = i / 33, kx = i - ky * 33;
            atomicAdd(&cnt[region_of(16 - ky, 16 - kx)], 1);
        }
        __syncthreads();
        if (tid < 33) {
            int ky = tid, n = 0;
            int c0 = region_of(16 - ky, 16);
            int kxa = 0;
            for (int kx = 1; kx <= 33; kx++) {
                int c = (kx < 33) ? region_of(16 - ky, 16 - kx) : -1;
                if (c != c0) {
                    runbuf[tid * 16 + n] = c0 | (kxa << 4) | ((kx - 1) << 10);
                    n++;
                    c0 = c; kxa = kx;
                }
            }
            countrow[tid] = n;
        }
        __syncthreads();
        if (tid == 0) {
            int a = 0;
            for (int t = 0; t < 33; t++) { rowstart[t] = a; a += countrow[t]; }
            rowstart[33] = a;
            mg[0] = 2 * a;
        }
        __syncthreads();
        if (tid < 33) {
            int ky = tid, base = rowstart[tid], n = countrow[tid];
            for (int j = 0; j < n; j++) {
                int rn  = runbuf[tid * 16 + j];
                int c   = rn & 15, kxa = (rn >> 4) & 63, kxb = (rn >> 10) & 63;
                float w = 1.0f / (float)cnt[c];
                int off0 = c * CHPP + (ky - 16) * WPP;
                tabg[2 * (base + j)]     = make_int2(off0 + (kxb - 16), __float_as_int(w));
                tabg[2 * (base + j) + 1] = make_int2(off0 + (kxa - 17), __float_as_int(-w));
            }
        }
    } else {
        // Zero one 16-row halo slab (16*546 = 8736 floats = 2184 float4)
        int seg   = blk - 17;                 // 0..51
        int plane = seg >> 1;                 // 0..25  (b*13+ch)
        int half  = seg & 1;
        float* base = ev + (size_t)plane * CHPP + (half ? (size_t)272 * WPP : 0);
        float4 z = make_float4(0.f, 0.f, 0.f, 0.f);
        float4* b4 = (float4*)base;           // CHPP, 272*WPP both %4 == 0
#pragma unroll
        for (int it = 0; it < 9; it++) {
            int idx = it * 256 + tid;
            if (idx < 2184) b4[idx] = z;
        }
    }
}

// ---------------------------------------------------------------------------
// Fused 1x1 convs + row prefix scan. One 256-thread block = one image row;
// thread t -> pixels (2t, 2t+1) via float2 loads (halves VMEM instr count vs
// 1 px/thread — conv was VMEM-issue-bound, not byte-bound).
// Weights via wave-uniform global reads (s_load_dwordx16). Channels 0..12 ->
// relu -> pair-sum wave scan + 4-wave LDS combine -> prefix written directly
// (left pad zeros, right pad = row total); 13 -> x_reg; 14,15 -> x_off.
__global__ __launch_bounds__(256) void convscan_k(
    const float* __restrict__ x, const float* __restrict__ wp,
    const float* __restrict__ bias, float* __restrict__ ev,
    float* __restrict__ out) {
    __shared__ float part[13][4];
    int tid  = threadIdx.x;                  // 0..255
    int lane = tid & 63;
    int wv   = tid >> 6;                     // 4 waves
    int bid  = blockIdx.x;                   // 512 blocks = BB*HH rows
    int b    = bid >> 8;
    int y    = bid & 255;
    int hw   = y * WW + tid * 2;
    const float* xb = x + (size_t)b * IMG + hw;

    float a0[16], a1[16];
#pragma unroll
    for (int o = 0; o < 16; o++) { a0[o] = 0.f; a1[o] = 0.f; }

#pragma unroll 4
    for (int c = 0; c < CC; c++) {
        float2 v = *(const float2*)(xb + c * HW);
        const float* wr = wp + c * 16;       // uniform -> s_load_dwordx16
#pragma unroll
        for (int o = 0; o < 16; o++) {
            float wv_ = wr[o];
            a0[o] = fmaf(v.x, wv_, a0[o]);
            a1[o] = fmaf(v.y, wv_, a1[o]);
        }
    }

    // relu+bias, pair sum, wave-inclusive scan; publish wave totals
#pragma unroll
    for (int o = 0; o < 13; o++) {
        float bo = bias[o];
        float e0 = fmaxf(a0[o] + bo, 0.f);
        float e1 = fmaxf(a1[o] + bo, 0.f);
        float s  = e0 + e1;
#pragma unroll
        for (int d = 1; d < 64; d <<= 1) {
            float t = __shfl_up(s, d, 64);
            if (lane >= d) s += t;
        }
        a0[o] = s - e1;                      // inclusive prefix through e0
        a1[o] = s;                           // inclusive prefix through e1
        if (lane == 63) part[o][wv] = s;
    }
    __syncthreads();

    size_t rowbase = (size_t)(b * 13) * CHPP + (size_t)(y + 16) * WPP;
#pragma unroll
    for (int o = 0; o < 13; o++) {
        float off = 0.f;
#pragma unroll
        for (int w2 = 0; w2 < 3; w2++)
            if (w2 < wv) off += part[o][w2];
        *(float2*)(&ev[rowbase + o * CHPP + 18 + tid * 2]) =
            make_float2(a0[o] + off, a1[o] + off);   // 8B-aligned: even offsets
    }
    // left pad zeros (cols 0..17, 13 channels = 234 stores)
    if (tid < 234) {
        int o = tid / 18, j = tid - o * 18;
        ev[rowbase + o * CHPP + j] = 0.f;
    }
    // right pad = row total (cols 530..545, 13 channels = 208 stores)
    if (tid < 208) {
        int o = tid >> 4, j = tid & 15;
        float tot = part[o][0] + part[o][1] + part[o][2] + part[o][3];
        ev[rowbase + o * CHPP + 530 + j] = tot;
    }

    *(float2*)(&out[OUT_REG + b * HW + hw]) =
        make_float2(a0[13] + bias[13], a1[13] + bias[13]);
    *(float2*)(&out[OUT_OFF + b * 2 * HW + hw]) =
        make_float2(a0[14] + bias[14], a1[14] + bias[14]);
    *(float2*)(&out[OUT_OFF + b * 2 * HW + HW + hw]) =
        make_float2(a0[15] + bias[15], a1[15] + bias[15]);
}

// ---------------------------------------------------------------------------
// Hough vote conv via run boundaries on row prefix sums + sigmoid.
// Table entries via uniform scalar loads; 1 vector load + 1 FMA per entry.
// XCD swizzle keeps each XCD's gather slab (~2.7 MB) inside its 4 MiB L2.
__global__ __launch_bounds__(256) void hough_k(const float* __restrict__ P,
                                               const int2* __restrict__ tabg,
                                               const int* __restrict__ mg,
                                               float* __restrict__ out) {
    int m   = mg[0];
    int tid = threadIdx.x;
    int bid = blockIdx.x;                      // 1024 blocks
    int sb  = (bid & 7) * 128 + (bid >> 3);    // XCD-contiguous pixel-block id
    int p   = sb * 256 + tid;
    int b   = p >> 17;
    int hw  = p & (HW - 1);
    int y   = hw >> 9, xx = hw & 511;
    const float* Pb = P + (size_t)b * EVB2 + (y + 16) * WPP + (xx + 18);

    float s = 0.f;
#pragma unroll 8
    for (int t = 0; t < m; t++) {
        int2 e = tabg[t];                      // uniform -> scalar load
        s = fmaf(Pb[e.x], __int_as_float(e.y), s);
    }
    out[b * HW + hw] = 1.0f / (1.0f + expf(-s));
}

// ---------------------------------------------------------------------------
extern "C" void kernel_launch(void* const* d_in, const int* in_sizes, int n_in,
                              void* d_out, int out_size, void* d_ws, size_t ws_size,
                              hipStream_t stream) {
    const float* x  = (const float*)d_in[0];
    const float* pw = (const float*)d_in[1];
    const float* pb = (const float*)d_in[2];
    const float* rw = (const float*)d_in[3];
    const float* rb = (const float*)d_in[4];
    const float* ow = (const float*)d_in[5];
    const float* ob = (const float*)d_in[6];
    float* out = (float*)d_out;

    float* ev   = (float*)d_ws;
    float* wp   = ev + EV2_FLOATS;
    float* bias = wp + 4096;
    int2*  tabg = (int2*)(bias + 16);          // 8B-aligned (even float offset)
    int*   mg   = (int*)(tabg + 2048);

    setup_k<<<69, 256, 0, stream>>>(pw, pb, rw, rb, ow, ob, wp, bias, tabg, mg, ev);
    convscan_k<<<512, 256, 0, stream>>>(x, wp, bias, ev, out);
    hough_k<<<1024, 256, 0, stream>>>(ev, tabg, mg, out);
}